// Round 1
// baseline (272.057 us; speedup 1.0000x reference)
//
#include <hip/hip_runtime.h>
#include <hip/hip_bf16.h>

// Problem: B=16, S=1024, D=1024, H=16, HD=64.
// energy = -sum_{b,h,s} logsumexp_t( beta_h * q[b,s,h,:].k[b,t,h,:], t != s ) / beta_h

using short8  = __attribute__((ext_vector_type(8))) short;
using f32x4   = __attribute__((ext_vector_type(4))) float;
using ushort8 = __attribute__((ext_vector_type(8))) unsigned short;
using float4v = __attribute__((ext_vector_type(4))) float;

#define B_  16
#define S_  1024
#define D_  1024
#define H_  16
#define HD_ 64

__device__ inline unsigned short f2bf(float f) {
  union { float f; unsigned u; } v; v.f = f;
  unsigned r = v.u + 0x7FFFu + ((v.u >> 16) & 1u);   // RNE
  return (unsigned short)(r >> 16);
}

// ---------------- fp32 -> bf16 convert, 8 elems/thread ----------------
__global__ __launch_bounds__(256) void cvt_bf16_k(const float* __restrict__ in,
                                                  unsigned short* __restrict__ out, int n8) {
  int i = blockIdx.x * 256 + threadIdx.x;
  if (i >= n8) return;
  const float4v* p = (const float4v*)in;
  float4v a = p[2 * i], b = p[2 * i + 1];
  ushort8 r;
  r[0] = f2bf(a[0]); r[1] = f2bf(a[1]); r[2] = f2bf(a[2]); r[3] = f2bf(a[3]);
  r[4] = f2bf(b[0]); r[5] = f2bf(b[1]); r[6] = f2bf(b[2]); r[7] = f2bf(b[3]);
  ((ushort8*)out)[i] = r;
}

__global__ void zero_out_k(float* o) { if (threadIdx.x == 0) *o = 0.f; }

// ---------------- staging: global -> LDS, [128 rows][64 bf16] tile ----------------
// XOR swizzle (G4): lds byte within row ^= (row&7)<<4. global_load_lds writes
// linearly, so the swizzle is applied to the per-lane GLOBAL source address
// (rule #21: linear dest + inverse-swizzled source + swizzled read).
__device__ inline void gload_lds16(const void* g, void* l) {
  __builtin_amdgcn_global_load_lds((const __attribute__((address_space(1))) void*)g,
                                   (__attribute__((address_space(3))) void*)l, 16, 0, 0);
}

__device__ inline void stage_tile(const char* src, int stride, char* lds, int tid) {
  int lane = tid & 63, wave = tid >> 6;
#pragma unroll
  for (int r = 0; r < 4; ++r) {
    int o   = r * 4096 + wave * 1024 + lane * 16;   // linear LDS byte offset this lane fills
    int row = o >> 7;
    int kb  = o & 127;
    int skb = kb ^ ((row & 7) << 4);                // involution
    gload_lds16(src + (size_t)row * stride + skb, lds + (r * 4096 + wave * 1024));
  }
}

// swizzled ds_read_b128 of an MFMA A/B fragment (row-major [128][64] bf16 tile)
__device__ inline short8 ld_frag(const char* lds, int row, int kk, int lane) {
  int kb   = kk * 64 + ((lane >> 4) << 4);          // byte offset of this lane's 8 bf16
  int addr = row * 128 + (kb ^ ((row & 7) << 4));
  return *(const short8*)(lds + addr);
}

// ---------------- projection GEMM: C[m][n] = sum_k A[m][k]*W[n][k] ----------------
// A = Xb (16384 x 1024 bf16), W = weight (1024 x 1024 bf16), out -> (B,H,S,HD) bf16.
// 128x128 tile, BK=64, 4 waves (2x2 of 64x64), 16x16x32 bf16 MFMA.
__global__ __launch_bounds__(256) void proj_gemm_k(const unsigned short* __restrict__ Xb,
                                                   const unsigned short* __restrict__ Wqb,
                                                   const unsigned short* __restrict__ Wkb,
                                                   unsigned short* __restrict__ Qg,
                                                   unsigned short* __restrict__ Kg) {
  __shared__ char As[16384];
  __shared__ char Bs[16384];
  const int tid = threadIdx.x, lane = tid & 63, wave = tid >> 6;
  const int wr = wave >> 1, wc = wave & 1;
  const int m0 = blockIdx.x * 128, n0 = blockIdx.y * 128;
  const unsigned short* W = blockIdx.z ? Wkb : Wqb;
  unsigned short* Out = blockIdx.z ? Kg : Qg;
  const char* Abase = (const char*)Xb + (size_t)m0 * (D_ * 2);
  const char* Bbase = (const char*)W  + (size_t)n0 * (D_ * 2);

  f32x4 acc[4][4];
#pragma unroll
  for (int i = 0; i < 4; ++i)
#pragma unroll
    for (int j = 0; j < 4; ++j)
#pragma unroll
      for (int q = 0; q < 4; ++q) acc[i][j][q] = 0.f;

  for (int kt = 0; kt < D_ / 64; ++kt) {
    stage_tile(Abase + kt * 128, D_ * 2, As, tid);
    stage_tile(Bbase + kt * 128, D_ * 2, Bs, tid);
    __syncthreads();   // drains vmcnt (global_load_lds) before ds_read
#pragma unroll
    for (int kk = 0; kk < 2; ++kk) {
      short8 a[4], b[4];
#pragma unroll
      for (int i = 0; i < 4; ++i) a[i] = ld_frag(As, wr * 64 + i * 16 + (lane & 15), kk, lane);
#pragma unroll
      for (int i = 0; i < 4; ++i) b[i] = ld_frag(Bs, wc * 64 + i * 16 + (lane & 15), kk, lane);
#pragma unroll
      for (int i = 0; i < 4; ++i)
#pragma unroll
        for (int j = 0; j < 4; ++j)
          acc[i][j] = __builtin_amdgcn_mfma_f32_16x16x32_bf16(a[i], b[j], acc[i][j], 0, 0, 0);
    }
    __syncthreads();   // protect LDS before next stage
  }

  // epilogue: C/D layout col=lane&15, row=(lane>>4)*4+reg [m89]; write (B,H,S,HD) bf16
#pragma unroll
  for (int mi = 0; mi < 4; ++mi)
#pragma unroll
    for (int ni = 0; ni < 4; ++ni)
#pragma unroll
      for (int j = 0; j < 4; ++j) {
        int m = m0 + wr * 64 + mi * 16 + ((lane >> 4) << 2) + j;
        int n = n0 + wc * 64 + ni * 16 + (lane & 15);
        int bb = m >> 10, s = m & (S_ - 1);
        int h = n >> 6, hd = n & (HD_ - 1);
        Out[(((size_t)bb * H_ + h) * S_ + s) * HD_ + hd] = f2bf(acc[mi][ni][j]);
      }
}

// ---------------- fused scores + masked logsumexp + energy ----------------
// grid: (qtile=8, h=16, b=16), 256 thr. Per block: 128 queries x all 1024 keys.
// Scores are tiny (|s|<~0.1) -> unshifted LSE is exact; diagonal masked to -1e30.
__global__ __launch_bounds__(256) void attn_lse_k(const unsigned short* __restrict__ Qg,
                                                  const unsigned short* __restrict__ Kg,
                                                  const float* __restrict__ beta,
                                                  float* __restrict__ out) {
  __shared__ char Qs[16384];
  __shared__ char Ks[16384];
  __shared__ float wsum[4];
  const int tid = threadIdx.x, lane = tid & 63, wave = tid >> 6;
  const int qt = blockIdx.x, h = blockIdx.y, b = blockIdx.z;
  const int q0 = qt * 128;
  const char* qbase = (const char*)Qg + (((size_t)b * H_ + h) * S_) * (HD_ * 2);
  const char* kbase = (const char*)Kg + (((size_t)b * H_ + h) * S_) * (HD_ * 2);

  stage_tile(qbase + (size_t)q0 * 128, 128, Qs, tid);
  const float bet = beta[h];

  float l_run[2][4];
#pragma unroll
  for (int mi = 0; mi < 2; ++mi)
#pragma unroll
    for (int j = 0; j < 4; ++j) l_run[mi][j] = 0.f;

  for (int kt = 0; kt < 8; ++kt) {
    stage_tile(kbase + (size_t)kt * 128 * 128, 128, Ks, tid);
    __syncthreads();

    f32x4 acc[2][8];
#pragma unroll
    for (int i = 0; i < 2; ++i)
#pragma unroll
      for (int j = 0; j < 8; ++j)
#pragma unroll
        for (int q = 0; q < 4; ++q) acc[i][j][q] = 0.f;

#pragma unroll
    for (int kk = 0; kk < 2; ++kk) {
      short8 a[2], kb[8];
#pragma unroll
      for (int mi = 0; mi < 2; ++mi)
        a[mi] = ld_frag(Qs, wave * 32 + mi * 16 + (lane & 15), kk, lane);
#pragma unroll
      for (int ni = 0; ni < 8; ++ni)
        kb[ni] = ld_frag(Ks, ni * 16 + (lane & 15), kk, lane);
#pragma unroll
      for (int mi = 0; mi < 2; ++mi)
#pragma unroll
        for (int ni = 0; ni < 8; ++ni)
          acc[mi][ni] = __builtin_amdgcn_mfma_f32_16x16x32_bf16(a[mi], kb[ni], acc[mi][ni], 0, 0, 0);
    }

    const bool dg = (kt == qt);
    float rs[2][4];
#pragma unroll
    for (int mi = 0; mi < 2; ++mi)
#pragma unroll
      for (int j = 0; j < 4; ++j) rs[mi][j] = 0.f;

#pragma unroll
    for (int mi = 0; mi < 2; ++mi)
#pragma unroll
      for (int ni = 0; ni < 8; ++ni) {
        f32x4 v = acc[mi][ni];
#pragma unroll
        for (int j = 0; j < 4; ++j) {
          float s = v[j] * bet;
          if (dg && (wave * 32 + mi * 16 + ((lane >> 4) << 2) + j) == (ni * 16 + (lane & 15)))
            s = -1e30f;   // exp -> 0 exactly: diagonal excluded
          rs[mi][j] += __expf(s);
        }
      }

    // row-sum lives across the 16 lanes of each (lane>>4) group: xor-reduce
#pragma unroll
    for (int mi = 0; mi < 2; ++mi)
#pragma unroll
      for (int j = 0; j < 4; ++j) {
        float v = rs[mi][j];
        v += __shfl_xor(v, 1); v += __shfl_xor(v, 2);
        v += __shfl_xor(v, 4); v += __shfl_xor(v, 8);
        l_run[mi][j] += v;
      }
    __syncthreads();   // before next K stage overwrites Ks
  }

  // lse = log(l) (no shift needed), energy contribution = -sum(lse)/beta
  float local = 0.f;
#pragma unroll
  for (int mi = 0; mi < 2; ++mi)
#pragma unroll
    for (int j = 0; j < 4; ++j) local += __logf(l_run[mi][j]);
  // values replicated across each 16-lane group; sum the 4 groups
  local += __shfl_xor(local, 16);
  local += __shfl_xor(local, 32);
  if (lane == 0) wsum[wave] = local;
  __syncthreads();
  if (tid == 0) {
    float t = wsum[0] + wsum[1] + wsum[2] + wsum[3];
    atomicAdd(out, -t / bet);
  }
}

// ---------------- launcher ----------------
extern "C" void kernel_launch(void* const* d_in, const int* in_sizes, int n_in,
                              void* d_out, int out_size, void* d_ws, size_t ws_size,
                              hipStream_t stream) {
  const float* x    = (const float*)d_in[0];
  const float* qw   = (const float*)d_in[1];
  const float* kw   = (const float*)d_in[2];
  const float* beta = (const float*)d_in[3];
  float* out = (float*)d_out;

  char* ws = (char*)d_ws;
  unsigned short* Xb  = (unsigned short*)(ws);              // 33554432 B
  unsigned short* Wqb = (unsigned short*)(ws + 33554432);   //  2097152 B
  unsigned short* Wkb = (unsigned short*)(ws + 35651584);   //  2097152 B
  unsigned short* Qg  = (unsigned short*)(ws + 37748736);   // 33554432 B
  unsigned short* Kg  = (unsigned short*)(ws + 71303168);   // 33554432 B (end 104857600)

  cvt_bf16_k<<<8192, 256, 0, stream>>>(x,  Xb,  (B_ * S_ * D_) / 8);
  cvt_bf16_k<<<512,  256, 0, stream>>>(qw, Wqb, (H_ * HD_ * D_) / 8);
  cvt_bf16_k<<<512,  256, 0, stream>>>(kw, Wkb, (H_ * HD_ * D_) / 8);
  zero_out_k<<<1, 64, 0, stream>>>(out);
  proj_gemm_k<<<dim3(128, 8, 2), 256, 0, stream>>>(Xb, Wqb, Wkb, Qg, Kg);
  attn_lse_k<<<dim3(8, H_, B_), 256, 0, stream>>>(Qg, Kg, beta, out);
}

// Round 6
// 253.832 us; speedup vs baseline: 1.0718x; 1.0718x over previous
//
#include <hip/hip_runtime.h>
#include <hip/hip_bf16.h>

// B=16, S=1024, D=1024, H=16, HD=64.
// energy = -sum_{b,h,s} logsumexp_t( beta_h * q.k, t != s ) / beta_h
// Q is pre-scaled by beta_h*log2(e) at projection time, so attention inner
// loop is pure v_exp_f32 (=exp2); lse recovered via log2 * ln2.

using short8  = __attribute__((ext_vector_type(8))) short;
using f32x4   = __attribute__((ext_vector_type(4))) float;
using ushort8 = __attribute__((ext_vector_type(8))) unsigned short;
using float4v = __attribute__((ext_vector_type(4))) float;

#define B_  16
#define S_  1024
#define D_  1024
#define H_  16
#define HD_ 64
#define LOG2E 1.4426950408889634f
#define LN2   0.6931471805599453f

// HW transcendentals: v_exp_f32 computes 2^x, v_log_f32 computes log2(x).
// Guarded: fall back to HIP device exp2f/log2f (same instruction via OCML)
// if this clang lacks the direct builtins. (R2 failed on the reserved
// __exp2f name colliding with glibc math.h macros — plain names are safe.)
#if __has_builtin(__builtin_amdgcn_exp2f)
#define EXP2F(x) __builtin_amdgcn_exp2f(x)
#else
#define EXP2F(x) exp2f(x)
#endif
#if __has_builtin(__builtin_amdgcn_logf)
#define LOG2F(x) __builtin_amdgcn_logf(x)
#else
#define LOG2F(x) log2f(x)
#endif

__device__ inline unsigned short f2bf(float f) {
  union { float f; unsigned u; } v; v.f = f;
  unsigned r = v.u + 0x7FFFu + ((v.u >> 16) & 1u);   // RNE
  return (unsigned short)(r >> 16);
}

// ---------------- fp32 -> bf16 convert, 8 elems/thread ----------------
__global__ __launch_bounds__(256) void cvt_bf16_k(const float* __restrict__ in,
                                                  unsigned short* __restrict__ out, int n8) {
  int i = blockIdx.x * 256 + threadIdx.x;
  if (i >= n8) return;
  const float4v* p = (const float4v*)in;
  float4v a = p[2 * i], b = p[2 * i + 1];
  ushort8 r;
  r[0] = f2bf(a[0]); r[1] = f2bf(a[1]); r[2] = f2bf(a[2]); r[3] = f2bf(a[3]);
  r[4] = f2bf(b[0]); r[5] = f2bf(b[1]); r[6] = f2bf(b[2]); r[7] = f2bf(b[3]);
  ((ushort8*)out)[i] = r;
}

__global__ void zero_out_k(float* o) { if (threadIdx.x == 0) *o = 0.f; }

// ---------------- staging: global -> LDS, [128 rows][64 bf16] tile ----------------
// XOR swizzle (G4): byte-in-row ^= (row&7)<<4. global_load_lds writes linearly,
// so apply the (involutive) swizzle to the per-lane GLOBAL source (rule #21).
__device__ inline void gload_lds16(const void* g, void* l) {
  __builtin_amdgcn_global_load_lds((const __attribute__((address_space(1))) void*)g,
                                   (__attribute__((address_space(3))) void*)l, 16, 0, 0);
}

__device__ inline void stage_tile(const char* src, int stride, char* lds, int tid) {
  int lane = tid & 63, wave = tid >> 6;
#pragma unroll
  for (int r = 0; r < 4; ++r) {
    int o   = r * 4096 + wave * 1024 + lane * 16;   // linear LDS byte offset
    int row = o >> 7;
    int kb  = o & 127;
    int skb = kb ^ ((row & 7) << 4);                // involution
    gload_lds16(src + (size_t)row * stride + skb, lds + (r * 4096 + wave * 1024));
  }
}

// swizzled ds_read_b128 of an MFMA A/B fragment (row-major [128][64] bf16 tile)
__device__ inline short8 ld_frag(const char* lds, int row, int kk, int lane) {
  int kb   = kk * 64 + ((lane >> 4) << 4);
  int addr = row * 128 + (kb ^ ((row & 7) << 4));
  return *(const short8*)(lds + addr);
}

// ---------------- projection GEMM ----------------
// 1D grid 2048, chunked XCD swizzle; each XCD: 16 m-panels x all 16 (n,z)
// tiles consecutive -> A-panel fetched once per XCD, weights (4 MB) L2-resident.
// z==0 (Q) output scaled by beta_h*log2e.
__global__ __launch_bounds__(256) void proj_gemm_k(const unsigned short* __restrict__ Xb,
                                                   const unsigned short* __restrict__ Wqb,
                                                   const unsigned short* __restrict__ Wkb,
                                                   const float* __restrict__ beta,
                                                   unsigned short* __restrict__ Qg,
                                                   unsigned short* __restrict__ Kg) {
  __shared__ char As[16384];
  __shared__ char Bs[16384];
  const int tid = threadIdx.x, lane = tid & 63, wave = tid >> 6;
  const int wr = wave >> 1, wc = wave & 1;
  const int wgid = (blockIdx.x & 7) * 256 + (blockIdx.x >> 3);  // chunked XCD swizzle (2048%8==0)
  const int mt = wgid >> 4, nz = wgid & 15;
  const int m0 = mt * 128, n0 = (nz & 7) * 128, z = nz >> 3;
  const unsigned short* W = z ? Wkb : Wqb;
  unsigned short* Out = z ? Kg : Qg;
  const char* Abase = (const char*)Xb + (size_t)m0 * (D_ * 2);
  const char* Bbase = (const char*)W  + (size_t)n0 * (D_ * 2);

  f32x4 acc[4][4];
#pragma unroll
  for (int i = 0; i < 4; ++i)
#pragma unroll
    for (int j = 0; j < 4; ++j)
#pragma unroll
      for (int q = 0; q < 4; ++q) acc[i][j][q] = 0.f;

  for (int kt = 0; kt < D_ / 64; ++kt) {
    stage_tile(Abase + kt * 128, D_ * 2, As, tid);
    stage_tile(Bbase + kt * 128, D_ * 2, Bs, tid);
    __syncthreads();
#pragma unroll
    for (int kk = 0; kk < 2; ++kk) {
      short8 a[4], b[4];
#pragma unroll
      for (int i = 0; i < 4; ++i) a[i] = ld_frag(As, wr * 64 + i * 16 + (lane & 15), kk, lane);
#pragma unroll
      for (int i = 0; i < 4; ++i) b[i] = ld_frag(Bs, wc * 64 + i * 16 + (lane & 15), kk, lane);
#pragma unroll
      for (int i = 0; i < 4; ++i)
#pragma unroll
        for (int j = 0; j < 4; ++j)
          acc[i][j] = __builtin_amdgcn_mfma_f32_16x16x32_bf16(a[i], b[j], acc[i][j], 0, 0, 0);
    }
    __syncthreads();
  }

  // head is uniform per wave: n = n0 + wc*64 + [0,64)
  const float scl = z ? 1.0f : beta[(n0 >> 6) + wc] * LOG2E;
#pragma unroll
  for (int mi = 0; mi < 4; ++mi)
#pragma unroll
    for (int ni = 0; ni < 4; ++ni)
#pragma unroll
      for (int j = 0; j < 4; ++j) {
        int m = m0 + wr * 64 + mi * 16 + ((lane >> 4) << 2) + j;
        int n = n0 + wc * 64 + ni * 16 + (lane & 15);
        int bb = m >> 10, s = m & (S_ - 1);
        int h = n >> 6, hd = n & (HD_ - 1);
        Out[(((size_t)bb * H_ + h) * S_ + s) * HD_ + hd] = f2bf(acc[mi][ni][j] * scl);
      }
}

// ---------------- fused scores + masked logsumexp + energy ----------------
// 1D grid 2048 (chunk-swizzled: the 8 q-tiles of one (b,h) share an XCD -> K
// panel L2-resident). Q frags hoisted to registers; K double-buffered with
// prefetch-before-compute (T3-min); inner loop = v_exp_f32 + add only.
__global__ __launch_bounds__(256) void attn_lse_k(const unsigned short* __restrict__ Qg,
                                                  const unsigned short* __restrict__ Kg,
                                                  const float* __restrict__ beta,
                                                  float* __restrict__ out) {
  __shared__ char Ks[2][16384];
  __shared__ float wsum[4];
  const int tid = threadIdx.x, lane = tid & 63, wave = tid >> 6;
  const int wgid = (blockIdx.x & 7) * 256 + (blockIdx.x >> 3);
  const int qt = wgid & 7, hb = wgid >> 3;
  const int h = hb & 15, b = hb >> 4;
  const char* qbase = (const char*)Qg + (((size_t)b * H_ + h) * S_) * (HD_ * 2);
  const char* kbase = (const char*)Kg + (((size_t)b * H_ + h) * S_) * (HD_ * 2);

  // prologue: Q tile -> buf0 -> registers (loop-invariant)
  stage_tile(qbase + (size_t)qt * 16384, 128, Ks[0], tid);
  __syncthreads();
  short8 qa[2][2];
#pragma unroll
  for (int mi = 0; mi < 2; ++mi)
#pragma unroll
    for (int kk = 0; kk < 2; ++kk)
      qa[mi][kk] = ld_frag(Ks[0], wave * 32 + mi * 16 + (lane & 15), kk, lane);
  stage_tile(kbase, 128, Ks[1], tid);
  __syncthreads();   // q reads done (lgkm drain) + K0 staged (vmcnt drain)

  float rs[2][4];
#pragma unroll
  for (int mi = 0; mi < 2; ++mi)
#pragma unroll
    for (int j = 0; j < 4; ++j) rs[mi][j] = 0.f;

  int cur = 1;
  for (int kt = 0; kt < 8; ++kt) {
    // prefetch next K tile into the other buffer (safe: all waves passed the
    // previous barrier, so no one still reads it); overlaps with compute below
    if (kt < 7) stage_tile(kbase + (size_t)(kt + 1) * 16384, 128, Ks[cur ^ 1], tid);

    f32x4 acc[2][8];
#pragma unroll
    for (int i = 0; i < 2; ++i)
#pragma unroll
      for (int j = 0; j < 8; ++j)
#pragma unroll
        for (int q = 0; q < 4; ++q) acc[i][j][q] = 0.f;

    __builtin_amdgcn_s_setprio(1);
#pragma unroll
    for (int kk = 0; kk < 2; ++kk)
#pragma unroll
      for (int ni = 0; ni < 8; ++ni) {
        short8 kf = ld_frag(Ks[cur], ni * 16 + (lane & 15), kk, lane);
        acc[0][ni] = __builtin_amdgcn_mfma_f32_16x16x32_bf16(qa[0][kk], kf, acc[0][ni], 0, 0, 0);
        acc[1][ni] = __builtin_amdgcn_mfma_f32_16x16x32_bf16(qa[1][kk], kf, acc[1][ni], 0, 0, 0);
      }
    __builtin_amdgcn_s_setprio(0);

    // acc already = log2e * beta * (q.k); sum exp2
    if (kt == qt) {
#pragma unroll
      for (int mi = 0; mi < 2; ++mi)
#pragma unroll
        for (int ni = 0; ni < 8; ++ni) {
          f32x4 v = acc[mi][ni];
#pragma unroll
          for (int j = 0; j < 4; ++j) {
            int row = wave * 32 + mi * 16 + ((lane >> 4) << 2) + j;
            int col = ni * 16 + (lane & 15);
            float s = (row == col) ? -1e30f : v[j];   // diagonal: exp2 -> 0
            rs[mi][j] += EXP2F(s);
          }
        }
    } else {
#pragma unroll
      for (int mi = 0; mi < 2; ++mi)
#pragma unroll
        for (int ni = 0; ni < 8; ++ni) {
          f32x4 v = acc[mi][ni];
#pragma unroll
          for (int j = 0; j < 4; ++j) rs[mi][j] += EXP2F(v[j]);
        }
    }
    __syncthreads();   // drains prefetch vmcnt (hidden under compute) + frees Ks[cur]
    cur ^= 1;
  }

  // single deferred reduction: row-sum across the 16 lanes of each group
  float local = 0.f;
#pragma unroll
  for (int mi = 0; mi < 2; ++mi)
#pragma unroll
    for (int j = 0; j < 4; ++j) {
      float v = rs[mi][j];
      v += __shfl_xor(v, 1); v += __shfl_xor(v, 2);
      v += __shfl_xor(v, 4); v += __shfl_xor(v, 8);
      local += LOG2F(v);                 // lse_nat = ln2 * log2(sum)
    }
  local += __shfl_xor(local, 16);
  local += __shfl_xor(local, 32);
  if (lane == 0) wsum[wave] = local;
  __syncthreads();
  if (tid == 0) {
    float t = wsum[0] + wsum[1] + wsum[2] + wsum[3];
    atomicAdd(out, -t * LN2 / beta[h]);
  }
}

// ---------------- launcher ----------------
extern "C" void kernel_launch(void* const* d_in, const int* in_sizes, int n_in,
                              void* d_out, int out_size, void* d_ws, size_t ws_size,
                              hipStream_t stream) {
  const float* x    = (const float*)d_in[0];
  const float* qw   = (const float*)d_in[1];
  const float* kw   = (const float*)d_in[2];
  const float* beta = (const float*)d_in[3];
  float* out = (float*)d_out;

  char* ws = (char*)d_ws;
  unsigned short* Xb  = (unsigned short*)(ws);              // 33554432 B
  unsigned short* Wqb = (unsigned short*)(ws + 33554432);   //  2097152 B
  unsigned short* Wkb = (unsigned short*)(ws + 35651584);   //  2097152 B
  unsigned short* Qg  = (unsigned short*)(ws + 37748736);   // 33554432 B
  unsigned short* Kg  = (unsigned short*)(ws + 71303168);   // 33554432 B (end 104857600)

  cvt_bf16_k<<<8192, 256, 0, stream>>>(x,  Xb,  (B_ * S_ * D_) / 8);
  cvt_bf16_k<<<512,  256, 0, stream>>>(qw, Wqb, (H_ * HD_ * D_) / 8);
  cvt_bf16_k<<<512,  256, 0, stream>>>(kw, Wkb, (H_ * HD_ * D_) / 8);
  zero_out_k<<<1, 64, 0, stream>>>(out);
  proj_gemm_k<<<2048, 256, 0, stream>>>(Xb, Wqb, Wkb, beta, Qg, Kg);
  attn_lse_k<<<2048, 256, 0, stream>>>(Qg, Kg, beta, out);
}